// Round 5
// baseline (674.860 us; speedup 1.0000x reference)
//
#include <hip/hip_runtime.h>

typedef short v8s __attribute__((ext_vector_type(8)));   // 8 x bf16 (4 VGPR)
typedef float v4f __attribute__((ext_vector_type(4)));

// HW packed f32->bf16 (RNE), 2 elems/instr. No builtin on gfx950 -> inline asm.
__device__ __forceinline__ unsigned cvtpk(float lo, float hi) {
    unsigned r;
    asm("v_cvt_pk_bf16_f32 %0, %1, %2" : "=v"(r) : "v"(lo), "v"(hi));
    return r;
}
__device__ __forceinline__ v8s pack8(float4 f0, float4 f1) {
    union { unsigned u[4]; v8s v; } r;
    r.u[0] = cvtpk(f0.x, f0.y); r.u[1] = cvtpk(f0.z, f0.w);
    r.u[2] = cvtpk(f1.x, f1.y); r.u[3] = cvtpk(f1.z, f1.w);
    return r.v;
}
__device__ __forceinline__ v4f mfma(v8s a, v8s b, v4f c) {
    return __builtin_amdgcn_mfma_f32_16x16x32_bf16(a, b, c, 0, 0, 0);
}
// B-frag for Z = Xin @ W^T from f32 W: lane holds W[n][k0..k0+7] as bf16.
__device__ __forceinline__ v8s ldwf(const float* W, int rowElems, int n, int k0) {
    const float* p = W + (size_t)n * rowElems + k0;
    union { unsigned u[4]; v8s v; } r;
    #pragma unroll
    for (int j = 0; j < 4; ++j) r.u[j] = cvtpk(p[2 * j], p[2 * j + 1]);
    return r.v;
}

// Fused-denominator LSTM cell: 5 exp2 + 2 rcp. (verified R3/R4, absmax 0.015625)
__device__ __forceinline__ float cell(float zi, float zf, float zg, float zo, float& c) {
    const float NL = -1.44269504f, PG = 2.88539008f;
    float ei = __builtin_amdgcn_exp2f(NL * zi);
    float ef = __builtin_amdgcn_exp2f(NL * zf);
    float eg = __builtin_amdgcn_exp2f(PG * zg);
    float Df = 1.f + ef;
    float Dig = (1.f + ei) * (1.f + eg);
    float cc = (c * Dig + Df * (eg - 1.f)) * __builtin_amdgcn_rcpf(Df * Dig);
    c = cc;
    float eo = __builtin_amdgcn_exp2f(NL * zo);
    float ec = __builtin_amdgcn_exp2f(fminf(PG * cc, 60.f));
    return (ec - 1.f) * __builtin_amdgcn_rcpf((1.f + eo) * (1.f + ec));
}

// 8-wave gate-split: wave w -> unit-group ug=w&3 (units 16ug..16ug+15),
// half=w>>2 (0: gates i(0),f(1); 1: gates g(2),o(3)). Per-wave weights halve
// (14-16 frags = 56-64 VGPR) so total regs fit 128 -> 4 waves/SIMD.
// (512,4): 4 waves/EU min -> 128-reg budget; need ~110-125, so no R1 spills.
__global__ __launch_bounds__(512, 4) void seq2seq(
    const float* __restrict__ X,
    const float* __restrict__ bias,
    const float* __restrict__ eWih0, const float* __restrict__ eWhh0, const float* __restrict__ eb0,
    const float* __restrict__ eWih1, const float* __restrict__ eWhh1, const float* __restrict__ eb1,
    const float* __restrict__ dWih0, const float* __restrict__ dWhh0, const float* __restrict__ db0,
    const float* __restrict__ dWih1, const float* __restrict__ dWhh1, const float* __restrict__ db1,
    const float* __restrict__ rW1, const float* __restrict__ rb1,
    const float* __restrict__ rW2, const float* __restrict__ rb2,
    float* __restrict__ out)
{
    // h staging, frag-linear: [parity][kk*512 + lane*8 + j], bf16 single-plane
    __shared__ __align__(16) short sh0[2][1024];
    __shared__ __align__(16) short sh1[2][1024];
    __shared__ __align__(16) short sy1[2][1024];     // parity-dbuf head GEMM1 out
    __shared__ __align__(16) v4f   zx[2][8][64];     // z-partial exchange, dbuf by layer

    const int tid  = threadIdx.x;
    const int lane = tid & 63;
    const int w    = tid >> 6;            // 0..7
    const int ug   = w & 3;               // unit group
    const int half = w >> 2;              // gate pair
    const int lo   = lane & 15, hi = lane >> 4;
    const int wg   = blockIdx.x;          // 16 batch rows per block

    // zero parity-1 staging (initial h = 0): 512 ints per buffer, 512 threads
    ((int*)sh0)[512 + tid] = 0;
    ((int*)sh1)[512 + tid] = 0;

    // staging write index for value (m = hi*4+q, u = 16*ug+lo); q-pair = half
    const int wsidx = (ug >> 1) * 512 + (((2 * ug) + (lo >> 3)) & 3) * 128 + hi * 32 + (lo & 7);

    // ---- encoder weights -> register B-frags; a in {0,1}, gate g = 2*half+a ----
    v8s wX[2][2], wY[2][2], wZ[2][2], wW[2][2];   // Wih0 / Whh0 / Wih1 / Whh1
    float bz0[2], bz1[2];
    #pragma unroll
    for (int a = 0; a < 2; ++a) {
        const int n = (2 * half + a) * 64 + ug * 16 + lo;   // z column (row of W)
        v8s z = {0, 0, 0, 0, 0, 0, 0, 0};
        wX[a][0] = (hi < 2) ? ldwf(eWih0, 16, n, (hi & 1) * 8) : z;  // K=16 zero-pad
        wX[a][1] = z;                                   // dead in enc (dec overwrites)
        #pragma unroll
        for (int kk = 0; kk < 2; ++kk) {
            wY[a][kk] = ldwf(eWhh0, 64, n, kk * 32 + hi * 8);
            wZ[a][kk] = ldwf(eWih1, 64, n, kk * 32 + hi * 8);
            wW[a][kk] = ldwf(eWhh1, 64, n, kk * 32 + hi * 8);
        }
        bz0[a] = eb0[n];
        bz1[a] = eb1[n];
    }

    float c0[2] = {0.f, 0.f};             // c-state only for this wave's q-pair
    float c1[2] = {0.f, 0.f};
    __syncthreads();   // staging zeros visible

    const float* xb = X + (size_t)(wg * 16 + lo) * 1536 + (hi & 1) * 8;

    // ============ encoder: P0 barA P1 barB P2 barC P3 -> loop ============
    // Hazards across P3->P0' (no barrier): P0' writes zx[0] (last read pre-barB),
    // reads sh0[pr'] (written P1, post-barB ordered); P3 touches zx[1]/sh1 only.
    #pragma unroll 2
    for (int t = 0; t < 96; ++t) {
        const int pw = t & 1, pr = pw ^ 1;
        const float* p = xb + t * 16;
        const float4 xv0 = *(const float4*)p;
        const float4 xv1 = *(const float4*)(p + 4);
        v4f acc[2];
        // ---- P0: l0 partial z = h0@Whh0^T + x@Wih0^T + b0 (this wave's 2 gates)
        #pragma unroll
        for (int a = 0; a < 2; ++a) acc[a] = (v4f){bz0[a], bz0[a], bz0[a], bz0[a]};
        #pragma unroll
        for (int kk = 0; kk < 2; ++kk) {
            const v8s ah = *(const v8s*)&sh0[pr][kk * 512 + lane * 8];
            #pragma unroll
            for (int a = 0; a < 2; ++a) acc[a] = mfma(ah, wY[a][kk], acc[a]);
        }
        {
            const v8s ax = pack8(xv0, xv1);
            #pragma unroll
            for (int a = 0; a < 2; ++a) acc[a] = mfma(ax, wX[a][0], acc[a]);
        }
        // exchange: give partner the q-rows it owns (literal indices: rule #20)
        if (half) zx[0][w][lane] = (v4f){acc[0][0], acc[0][1], acc[1][0], acc[1][1]};
        else      zx[0][w][lane] = (v4f){acc[0][2], acc[0][3], acc[1][2], acc[1][3]};
        __syncthreads();                                  // barA: z0 partials ready
        // ---- P1: cells for q = 2*half+{0,1}; write h0
        {
            const v4f rx = zx[0][w ^ 4][lane];
            float h0v, h1v;
            if (half == 0) {
                h0v = cell(acc[0][0], acc[1][0], rx[0], rx[2], c0[0]);
                h1v = cell(acc[0][1], acc[1][1], rx[1], rx[3], c0[1]);
            } else {
                h0v = cell(rx[0], rx[2], acc[0][2], acc[1][2], c0[0]);
                h1v = cell(rx[1], rx[3], acc[0][3], acc[1][3], c0[1]);
            }
            unsigned pk = cvtpk(h0v, h1v);
            short* b = &sh0[pw][wsidx + half * 16];
            b[0] = (short)pk; b[8] = (short)(pk >> 16);
        }
        __syncthreads();                                  // barB: h0 ready
        // ---- P2: l1 partial z = h0@Wih1^T + h1@Whh1^T + b1
        #pragma unroll
        for (int a = 0; a < 2; ++a) acc[a] = (v4f){bz1[a], bz1[a], bz1[a], bz1[a]};
        #pragma unroll
        for (int kk = 0; kk < 2; ++kk) {
            const v8s ah = *(const v8s*)&sh0[pw][kk * 512 + lane * 8];
            const v8s bh = *(const v8s*)&sh1[pr][kk * 512 + lane * 8];
            #pragma unroll
            for (int a = 0; a < 2; ++a) {
                acc[a] = mfma(ah, wZ[a][kk], acc[a]);
                acc[a] = mfma(bh, wW[a][kk], acc[a]);
            }
        }
        if (half) zx[1][w][lane] = (v4f){acc[0][0], acc[0][1], acc[1][0], acc[1][1]};
        else      zx[1][w][lane] = (v4f){acc[0][2], acc[0][3], acc[1][2], acc[1][3]};
        __syncthreads();                                  // barC: z1 partials ready
        // ---- P3: l1 cells; write h1 (no barrier; see loop-head comment)
        {
            const v4f rx = zx[1][w ^ 4][lane];
            float h0v, h1v;
            if (half == 0) {
                h0v = cell(acc[0][0], acc[1][0], rx[0], rx[2], c1[0]);
                h1v = cell(acc[0][1], acc[1][1], rx[1], rx[3], c1[1]);
            } else {
                h0v = cell(rx[0], rx[2], acc[0][2], acc[1][2], c1[0]);
                h1v = cell(rx[1], rx[3], acc[0][3], acc[1][3], c1[1]);
            }
            unsigned pk = cvtpk(h0v, h1v);
            short* b = &sh1[pw][wsidx + half * 16];
            b[0] = (short)pk; b[8] = (short)(pk >> 16);
        }
    }
    __syncthreads();   // order enc t=95 writes before dec reads (h0/h1 in parity 1)

    // ---- decoder + head weights -> registers ----
    #pragma unroll
    for (int a = 0; a < 2; ++a) {
        const int n = (2 * half + a) * 64 + ug * 16 + lo;
        #pragma unroll
        for (int kk = 0; kk < 2; ++kk) {
            wX[a][kk] = ldwf(dWih0, 64, n, kk * 32 + hi * 8);
            wY[a][kk] = ldwf(dWhh0, 64, n, kk * 32 + hi * 8);
            wZ[a][kk] = ldwf(dWih1, 64, n, kk * 32 + hi * 8);
            wW[a][kk] = ldwf(dWhh1, 64, n, kk * 32 + hi * 8);
        }
        bz0[a] = db0[n];
        bz1[a] = db1[n];
    }
    v8s w1f[2], w2f[2];
    #pragma unroll
    for (int kk = 0; kk < 2; ++kk) {
        w1f[kk] = ldwf(rW1, 64, ug * 16 + lo, kk * 32 + hi * 8);  // waves 0-3 use
        w2f[kk] = ldwf(rW2, 64, lo, kk * 32 + hi * 8);            // wave 4 uses
    }
    const float hb1 = rb1[ug * 16 + lo];
    const float hb2 = rb2[lo];
    float lb[4];
    #pragma unroll
    for (int q = 0; q < 4; ++q) lb[q] = bias[(size_t)(wg * 16 + hi * 4 + q) * 16 + lo];
    c0[0] = c0[1] = c1[0] = c1[1] = 0.f;

    // ============ decoder: P0 barA P1 barB P2 barC P3 barD P4(head) -> loop ====
    // P4 has no trailing barrier: GEMM1(s) writes sy1[pw]; GEMM2(s-1) reads
    // sy1[pr] (disjoint); next P0 reads sh0[pr']/sh1[pr'] = this step's pw
    // buffers, ordered by barD; zx[0] rewrite in P0' ordered by barB..barD.
    #pragma unroll 2
    for (int s = 0; s < 24; ++s) {
        const int pw = s & 1, pr = pw ^ 1;   // s=0 reads parity 1 = encoder finals
        v4f acc[2];
        // ---- P0: dec l0: x = h_t (sh1[pr]), hidden = dh0 (sh0[pr])
        #pragma unroll
        for (int a = 0; a < 2; ++a) acc[a] = (v4f){bz0[a], bz0[a], bz0[a], bz0[a]};
        #pragma unroll
        for (int kk = 0; kk < 2; ++kk) {
            const v8s ah = *(const v8s*)&sh1[pr][kk * 512 + lane * 8];
            const v8s bh = *(const v8s*)&sh0[pr][kk * 512 + lane * 8];
            #pragma unroll
            for (int a = 0; a < 2; ++a) {
                acc[a] = mfma(ah, wX[a][kk], acc[a]);
                acc[a] = mfma(bh, wY[a][kk], acc[a]);
            }
        }
        if (half) zx[0][w][lane] = (v4f){acc[0][0], acc[0][1], acc[1][0], acc[1][1]};
        else      zx[0][w][lane] = (v4f){acc[0][2], acc[0][3], acc[1][2], acc[1][3]};
        __syncthreads();                                  // barA
        // ---- P1: cells c0; write h0 (dh0)
        {
            const v4f rx = zx[0][w ^ 4][lane];
            float h0v, h1v;
            if (half == 0) {
                h0v = cell(acc[0][0], acc[1][0], rx[0], rx[2], c0[0]);
                h1v = cell(acc[0][1], acc[1][1], rx[1], rx[3], c0[1]);
            } else {
                h0v = cell(rx[0], rx[2], acc[0][2], acc[1][2], c0[0]);
                h1v = cell(rx[1], rx[3], acc[0][3], acc[1][3], c0[1]);
            }
            unsigned pk = cvtpk(h0v, h1v);
            short* b = &sh0[pw][wsidx + half * 16];
            b[0] = (short)pk; b[8] = (short)(pk >> 16);
        }
        __syncthreads();                                  // barB
        // ---- P2: dec l1: x = sh0[pw], hidden = dh1 (sh1[pr])
        #pragma unroll
        for (int a = 0; a < 2; ++a) acc[a] = (v4f){bz1[a], bz1[a], bz1[a], bz1[a]};
        #pragma unroll
        for (int kk = 0; kk < 2; ++kk) {
            const v8s ah = *(const v8s*)&sh0[pw][kk * 512 + lane * 8];
            const v8s bh = *(const v8s*)&sh1[pr][kk * 512 + lane * 8];
            #pragma unroll
            for (int a = 0; a < 2; ++a) {
                acc[a] = mfma(ah, wZ[a][kk], acc[a]);
                acc[a] = mfma(bh, wW[a][kk], acc[a]);
            }
        }
        if (half) zx[1][w][lane] = (v4f){acc[0][0], acc[0][1], acc[1][0], acc[1][1]};
        else      zx[1][w][lane] = (v4f){acc[0][2], acc[0][3], acc[1][2], acc[1][3]};
        __syncthreads();                                  // barC
        // ---- P3: cells c1; write h1 (h_t)
        {
            const v4f rx = zx[1][w ^ 4][lane];
            float h0v, h1v;
            if (half == 0) {
                h0v = cell(acc[0][0], acc[1][0], rx[0], rx[2], c1[0]);
                h1v = cell(acc[0][1], acc[1][1], rx[1], rx[3], c1[1]);
            } else {
                h0v = cell(rx[0], rx[2], acc[0][2], acc[1][2], c1[0]);
                h1v = cell(rx[1], rx[3], acc[0][3], acc[1][3], c1[1]);
            }
            unsigned pk = cvtpk(h0v, h1v);
            short* b = &sh1[pw][wsidx + half * 16];
            b[0] = (short)pk; b[8] = (short)(pk >> 16);
        }
        __syncthreads();                                  // barD: h_t ready
        // ---- P4: head. waves 0-3: GEMM1(s); wave 4: GEMM2(s-1) concurrently
        if (w < 4) {
            v4f ay = (v4f){hb1, hb1, hb1, hb1};
            #pragma unroll
            for (int kk = 0; kk < 2; ++kk) {
                const v8s ah = *(const v8s*)&sh1[pw][kk * 512 + lane * 8];
                ay = mfma(ah, w1f[kk], ay);
            }
            #pragma unroll
            for (int qp = 0; qp < 2; ++qp) {
                unsigned pk = cvtpk(fmaxf(ay[2 * qp], 0.f), fmaxf(ay[2 * qp + 1], 0.f));
                short* b = &sy1[pw][wsidx + qp * 16];
                b[0] = (short)pk; b[8] = (short)(pk >> 16);
            }
        } else if (w == 4 && s > 0) {
            v4f a2 = (v4f){hb2, hb2, hb2, hb2};
            #pragma unroll
            for (int kk = 0; kk < 2; ++kk) {
                const v8s a = *(const v8s*)&sy1[pr][kk * 512 + lane * 8];
                a2 = mfma(a, w2f[kk], a2);
            }
            #pragma unroll
            for (int q = 0; q < 4; ++q) {
                size_t row = (size_t)(wg * 16 + hi * 4 + q);
                out[row * 384 + (s - 1) * 16 + lo] = a2[q] + lb[q];
            }
        }
    }
    // ---- drain: head GEMM2 for s=23 (sy1 parity 1) ----
    __syncthreads();
    if (w == 4) {
        v4f a2 = (v4f){hb2, hb2, hb2, hb2};
        #pragma unroll
        for (int kk = 0; kk < 2; ++kk) {
            const v8s a = *(const v8s*)&sy1[1][kk * 512 + lane * 8];
            a2 = mfma(a, w2f[kk], a2);
        }
        #pragma unroll
        for (int q = 0; q < 4; ++q) {
            size_t row = (size_t)(wg * 16 + hi * 4 + q);
            out[row * 384 + 23 * 16 + lo] = a2[q] + lb[q];
        }
    }
}

extern "C" void kernel_launch(void* const* d_in, const int* in_sizes, int n_in,
                              void* d_out, int out_size, void* d_ws, size_t ws_size,
                              hipStream_t stream) {
    seq2seq<<<dim3(1024), dim3(512), 0, stream>>>(
        (const float*)d_in[0],   // X
        (const float*)d_in[1],   // bias   (d_in[2] = X_mask, unused by reference)
        (const float*)d_in[3],  (const float*)d_in[4],  (const float*)d_in[5],
        (const float*)d_in[6],  (const float*)d_in[7],  (const float*)d_in[8],
        (const float*)d_in[9],  (const float*)d_in[10], (const float*)d_in[11],
        (const float*)d_in[12], (const float*)d_in[13], (const float*)d_in[14],
        (const float*)d_in[15], (const float*)d_in[16],
        (const float*)d_in[17], (const float*)d_in[18],
        (float*)d_out);
}